// Round 2
// baseline (5077.162 us; speedup 1.0000x reference)
//
#include <hip/hip_runtime.h>
#include <math.h>

// Problem constants (reference: B=4, S=4096, D=1024, A=1024, all fp32)
constexpr int CB = 4;
constexpr int CS = 4096;
constexpr int CD = 1024;
constexpr int CA = 1024;

// ---------------------------------------------------------------------------
// Generic fp32 tiled GEMM: C[m,n] = sum_k A[m,k] * B[k,n]   (BT=false)
//                          C[m,n] = sum_k A[m,k] * B[n,k]   (BT=true)
// 64x64 tile per 256-thread block, BK=16, 4x4 register micro-tile per thread.
// A is staged TRANSPOSED in LDS (Ast[kk][m]) so the inner loop is two
// ds_read_b128 per k-step. All dims multiples of 64/16 here — no guards.
// ---------------------------------------------------------------------------
template <bool BT>
__global__ __launch_bounds__(256) void gemm64(const float* __restrict__ A,
                                              const float* __restrict__ B,
                                              float* __restrict__ C, int N,
                                              int Kd) {
  __shared__ float Ast[16][68];  // [kk][m], +4 pad breaks bank patterns
  __shared__ float Bs[16][68];   // [kk][n]

  const int tid = threadIdx.x;
  const int tx = tid & 15;   // output col group
  const int ty = tid >> 4;   // output row group
  const int row0 = blockIdx.y * 64;
  const int col0 = blockIdx.x * 64;

  float acc[4][4] = {};

  for (int k0 = 0; k0 < Kd; k0 += 16) {
    // --- stage A tile (64 rows x 16 k), transposed into LDS ---
    {
      const int m = tid >> 2;
      const int kc = (tid & 3) << 2;
      const float4 av =
          *(const float4*)(A + (long)(row0 + m) * Kd + (k0 + kc));
      Ast[kc + 0][m] = av.x;
      Ast[kc + 1][m] = av.y;
      Ast[kc + 2][m] = av.z;
      Ast[kc + 3][m] = av.w;
    }
    // --- stage B tile (16 k x 64 n) ---
    if (BT) {
      // B is [N, Kd]; need Bs[kk][n] = B[col0+n][k0+kk]  (transpose on store)
      const int nn = tid >> 2;
      const int kc = (tid & 3) << 2;
      const float4 bv =
          *(const float4*)(B + (long)(col0 + nn) * Kd + (k0 + kc));
      Bs[kc + 0][nn] = bv.x;
      Bs[kc + 1][nn] = bv.y;
      Bs[kc + 2][nn] = bv.z;
      Bs[kc + 3][nn] = bv.w;
    } else {
      // B is [Kd, N]; direct vector copy
      const int kk = tid >> 4;
      const int nc = (tid & 15) << 2;
      const float4 bv = *(const float4*)(B + (long)(k0 + kk) * N + col0 + nc);
      *(float4*)&Bs[kk][nc] = bv;
    }
    __syncthreads();

#pragma unroll
    for (int kk = 0; kk < 16; ++kk) {
      const float4 a4 = *(const float4*)&Ast[kk][ty << 2];
      const float4 b4 = *(const float4*)&Bs[kk][tx << 2];
      const float av[4] = {a4.x, a4.y, a4.z, a4.w};
      const float bv[4] = {b4.x, b4.y, b4.z, b4.w};
#pragma unroll
      for (int i = 0; i < 4; ++i)
#pragma unroll
        for (int j = 0; j < 4; ++j)
          acc[i][j] = fmaf(av[i], bv[j], acc[i][j]);
    }
    __syncthreads();
  }

#pragma unroll
  for (int i = 0; i < 4; ++i) {
    const float4 v =
        make_float4(acc[i][0], acc[i][1], acc[i][2], acc[i][3]);
    *(float4*)(C + (long)(row0 + (ty << 2) + i) * N + col0 + (tx << 2)) = v;
  }
}

// ---------------------------------------------------------------------------
// Row softmax over 4096-wide rows, one 256-thread block per row.
// Row cached in 16 registers/thread: one read + one write of HBM.
// ---------------------------------------------------------------------------
__global__ __launch_bounds__(256) void softmax_rows4096(float* __restrict__ P) {
  const long row = blockIdx.x;
  float* p = P + row * 4096L;
  const int tid = threadIdx.x;

  float r[16];
#pragma unroll
  for (int i = 0; i < 16; ++i) r[i] = p[tid + (i << 8)];

  float m = r[0];
#pragma unroll
  for (int i = 1; i < 16; ++i) m = fmaxf(m, r[i]);
#pragma unroll
  for (int off = 32; off > 0; off >>= 1) m = fmaxf(m, __shfl_down(m, off));

  __shared__ float smax[4];
  __shared__ float ssum[4];
  const int lane = tid & 63;
  const int wv = tid >> 6;
  if (lane == 0) smax[wv] = m;
  __syncthreads();
  m = fmaxf(fmaxf(smax[0], smax[1]), fmaxf(smax[2], smax[3]));

  float s = 0.f;
#pragma unroll
  for (int i = 0; i < 16; ++i) {
    r[i] = __expf(r[i] - m);
    s += r[i];
  }
#pragma unroll
  for (int off = 32; off > 0; off >>= 1) s += __shfl_down(s, off);
  if (lane == 0) ssum[wv] = s;
  __syncthreads();
  s = (ssum[0] + ssum[1]) + (ssum[2] + ssum[3]);

  const float inv = 1.0f / s;
#pragma unroll
  for (int i = 0; i < 16; ++i) p[tid + (i << 8)] = r[i] * inv;
}

// ---------------------------------------------------------------------------
// Launch. Workspace-ADAPTIVE (R0 crashed assuming 470 MB of d_ws):
//   per batch b:  Q_b,K_b,V_b  (3 x 16 MB = 48 MB, fixed)
//                 Sc slab      (slabQ x 4096 fp32; slabQ from ws_size, <=4096)
// Minimum workspace: 48 MB + 1 MB (slabQ=64). At >=112 MB: one slab per batch.
// ---------------------------------------------------------------------------
extern "C" void kernel_launch(void* const* d_in, const int* in_sizes, int n_in,
                              void* d_out, int out_size, void* d_ws,
                              size_t ws_size, hipStream_t stream) {
  const float* X = (const float*)d_in[0];   // [B,S,D]
  const float* Wq = (const float*)d_in[1];  // [D,A]
  const float* Wk = (const float*)d_in[2];
  const float* Wv = (const float*)d_in[3];
  float* out = (float*)d_out;  // [B,S,A]

  const long nSA = (long)CS * CA;  // 4096*1024 per-batch matrix
  float* Qb = (float*)d_ws;
  float* Kb = Qb + nSA;
  float* Vb = Kb + nSA;
  float* Sc = Vb + nSA;

  // choose query-slab size from remaining workspace
  const size_t fixedB = 3UL * nSA * sizeof(float);  // 48 MB
  long slabQ = 64;
  if (ws_size > fixedB) {
    long fit = (long)((ws_size - fixedB) / ((size_t)CS * sizeof(float)));
    fit = (fit / 64) * 64;
    if (fit > slabQ) slabQ = fit;
    if (slabQ > CS) slabQ = CS;
  }

  const dim3 blk(256);

  for (int b = 0; b < CB; ++b) {
    const float* Xb = X + (long)b * CS * CD;
    float* outb = out + (long)b * nSA;

    // 1) projections: [S, D] @ [D, A]
    const dim3 gp(CA / 64, CS / 64, 1);
    gemm64<false><<<gp, blk, 0, stream>>>(Xb, Wq, Qb, CA, CD);
    gemm64<false><<<gp, blk, 0, stream>>>(Xb, Wk, Kb, CA, CD);
    gemm64<false><<<gp, blk, 0, stream>>>(Xb, Wv, Vb, CA, CD);

    for (long q0 = 0; q0 < CS; q0 += slabQ) {
      const long qn = (q0 + slabQ <= CS) ? slabQ : (CS - q0);
      // 2) scores slab: Q[q0:q0+qn, A] @ K^T -> Sc [qn, S]
      gemm64<true><<<dim3(CS / 64, qn / 64, 1), blk, 0, stream>>>(
          Qb + q0 * CA, Kb, Sc, CS, CA);
      // 3) softmax rows of the slab
      softmax_rows4096<<<dim3((unsigned)qn), blk, 0, stream>>>(Sc);
      // 4) out slab: Sc [qn, S] @ V [S, A] -> out[q0:q0+qn, :]
      gemm64<false><<<dim3(CA / 64, qn / 64, 1), blk, 0, stream>>>(
          Sc, Vb, outb + q0 * CA, CA, CS);
    }
  }
}

// Round 3
// 1758.687 us; speedup vs baseline: 2.8869x; 2.8869x over previous
//
#include <hip/hip_runtime.h>
#include <math.h>

// Problem: B=4, S=4096, D=1024, A=1024, fp32 in/out. No 1/sqrt(d) scaling.
// Strategy: split-bf16 (Ootomo) MFMA for the precision-critical GEMMs:
//   C = Ahi@Bhi + Alo@Bhi + Ahi@Blo   (3-segment K-loop, one kernel)
// All GEMMs in NT form (A row-major [M,K], B row-major [N,K], k contiguous)
// so both operands stage via global_load_lds (wave-uniform base + lane*16).
constexpr int CS = 4096;
constexpr int CD = 1024;
constexpr int CA = 1024;
constexpr int CB_ = 4;

typedef unsigned short u16;
typedef __bf16 bf16x8 __attribute__((ext_vector_type(8)));
typedef float f32x4 __attribute__((ext_vector_type(4)));
typedef unsigned short u16x4 __attribute__((ext_vector_type(4)));

__device__ __forceinline__ u16 f32_to_bf16(float f) {
  unsigned u = __float_as_uint(f);
  u = (u + 0x7FFF + ((u >> 16) & 1)) >> 16;  // RNE
  return (u16)u;
}
__device__ __forceinline__ float bf16_to_f32(u16 h) {
  return __uint_as_float(((unsigned)h) << 16);
}

// async global->LDS, 16 B per lane; lds base MUST be wave-uniform.
__device__ __forceinline__ void async16(const u16* g, u16* lds_uniform) {
  __builtin_amdgcn_global_load_lds(
      (const __attribute__((address_space(1))) void*)g,
      (__attribute__((address_space(3))) void*)lds_uniform, 16, 0, 0);
}

// ---------------------------------------------------------------------------
// NT bf16 MFMA GEMM: C[m,n] = sum_seg sum_k Aseg[m,k]*Bseg[n,k]
// 128x128 tile / 256 threads (4 waves, each 64x64 = 4x4 frags of 16x16x32).
// OUTMODE 0: fp32 C (normal).  1: bf16 split -> Chi,Clo (normal).
//         2: bf16 transposed -> Ct[n*ldc + m].
// ---------------------------------------------------------------------------
template <int NSEG, int OUTMODE>
__global__ __launch_bounds__(256) void gemm_nt(
    const u16* __restrict__ A0, const u16* __restrict__ A1,
    const u16* __restrict__ A2, const u16* __restrict__ B0,
    const u16* __restrict__ B1, const u16* __restrict__ B2,
    void* __restrict__ C0v, void* __restrict__ C1v, int Kd, int lda, int ldb,
    int ldc) {
  __shared__ u16 As[128 * 32];
  __shared__ u16 Bs[128 * 32];
  const int tid = threadIdx.x;
  const int wave = tid >> 6, lane = tid & 63;
  const int quad = lane >> 4, l16 = lane & 15;
  const int m0 = blockIdx.y * 128, n0 = blockIdx.x * 128;
  const int wm = (wave >> 1) * 64, wn = (wave & 1) * 64;

  // staging coords: chunk c = 1 KB = 16 rows; lane covers row c*16+lane/4,
  // cols (lane%4)*8..+8. Wave w stages chunks {w, w+4} of A and of B.
  const int srow = lane >> 2;
  const int scol = (lane & 3) * 8;
  const int c0 = wave, c1 = wave + 4;

  f32x4 acc[4][4];
#pragma unroll
  for (int i = 0; i < 4; ++i)
#pragma unroll
    for (int j = 0; j < 4; ++j) acc[i][j] = (f32x4){0.f, 0.f, 0.f, 0.f};

  const u16* Aseg[3] = {A0, A1, A2};
  const u16* Bseg[3] = {B0, B1, B2};
#pragma unroll
  for (int seg = 0; seg < NSEG; ++seg) {
    const u16* Ab = Aseg[seg] + (long)m0 * lda;
    const u16* Bb = Bseg[seg] + (long)n0 * ldb;
    for (int k0 = 0; k0 < Kd; k0 += 32) {
      async16(Ab + (long)(c0 * 16 + srow) * lda + k0 + scol, As + c0 * 512);
      async16(Ab + (long)(c1 * 16 + srow) * lda + k0 + scol, As + c1 * 512);
      async16(Bb + (long)(c0 * 16 + srow) * ldb + k0 + scol, Bs + c0 * 512);
      async16(Bb + (long)(c1 * 16 + srow) * ldb + k0 + scol, Bs + c1 * 512);
      __syncthreads();
      bf16x8 af[4], bfr[4];
#pragma unroll
      for (int i = 0; i < 4; ++i)
        af[i] = *(const bf16x8*)&As[(wm + i * 16 + l16) * 32 + quad * 8];
#pragma unroll
      for (int j = 0; j < 4; ++j)
        bfr[j] = *(const bf16x8*)&Bs[(wn + j * 16 + l16) * 32 + quad * 8];
#pragma unroll
      for (int i = 0; i < 4; ++i)
#pragma unroll
        for (int j = 0; j < 4; ++j)
          acc[i][j] = __builtin_amdgcn_mfma_f32_16x16x32_bf16(af[i], bfr[j],
                                                              acc[i][j], 0, 0, 0);
      __syncthreads();
    }
  }

  // Epilogue. C/D frag layout (m89-verified): col = lane&15, row = quad*4+reg.
  if (OUTMODE == 0) {
    float* C = (float*)C0v;
#pragma unroll
    for (int i = 0; i < 4; ++i) {
      const int rb = m0 + wm + i * 16 + quad * 4;
#pragma unroll
      for (int j = 0; j < 4; ++j) {
        const int c = n0 + wn + j * 16 + l16;
#pragma unroll
        for (int r = 0; r < 4; ++r) C[(long)(rb + r) * ldc + c] = acc[i][j][r];
      }
    }
  } else if (OUTMODE == 1) {
    u16* Chi = (u16*)C0v;
    u16* Clo = (u16*)C1v;
#pragma unroll
    for (int i = 0; i < 4; ++i) {
      const int rb = m0 + wm + i * 16 + quad * 4;
#pragma unroll
      for (int j = 0; j < 4; ++j) {
        const int c = n0 + wn + j * 16 + l16;
#pragma unroll
        for (int r = 0; r < 4; ++r) {
          const float v = acc[i][j][r];
          const u16 h = f32_to_bf16(v);
          Chi[(long)(rb + r) * ldc + c] = h;
          Clo[(long)(rb + r) * ldc + c] = f32_to_bf16(v - bf16_to_f32(h));
        }
      }
    }
  } else {  // OUTMODE 2: transposed bf16 (for V^T): rows of Ct are n-index
    u16* Ct = (u16*)C0v;
#pragma unroll
    for (int i = 0; i < 4; ++i) {
      const int rb = m0 + wm + i * 16 + quad * 4;
#pragma unroll
      for (int j = 0; j < 4; ++j) {
        const int c = n0 + wn + j * 16 + l16;
        u16x4 p;
#pragma unroll
        for (int r = 0; r < 4; ++r) p[r] = f32_to_bf16(acc[i][j][r]);
        *(u16x4*)&Ct[(long)c * ldc + rb] = p;
      }
    }
  }
}

// ---------------------------------------------------------------------------
// W [D,A] fp32 -> Wt hi/lo bf16 [A,D] (transposed). Tlo may be null.
// ---------------------------------------------------------------------------
__global__ __launch_bounds__(256) void wtrans_split(const float* __restrict__ W,
                                                    u16* __restrict__ Thi,
                                                    u16* __restrict__ Tlo) {
  __shared__ float t[32][33];
  const int tx = threadIdx.x & 31, ty = threadIdx.x >> 5;
  const int a0 = blockIdx.x * 32;  // col tile of W (a)
  const int d0 = blockIdx.y * 32;  // row tile of W (d)
#pragma unroll
  for (int i = 0; i < 32; i += 8)
    t[ty + i][tx] = W[(long)(d0 + ty + i) * CA + a0 + tx];
  __syncthreads();
#pragma unroll
  for (int i = 0; i < 32; i += 8) {
    const float v = t[tx][ty + i];  // = W[d0+tx][a0+ty+i]
    const int a = a0 + ty + i, d = d0 + tx;
    const u16 h = f32_to_bf16(v);
    Thi[(long)a * CD + d] = h;
    if (Tlo) Tlo[(long)a * CD + d] = f32_to_bf16(v - bf16_to_f32(h));
  }
}

// fp32 -> (hi, lo) bf16, elementwise, float4-vectorized.
__global__ __launch_bounds__(256) void split_f32(const float* __restrict__ X,
                                                 u16* __restrict__ hi,
                                                 u16* __restrict__ lo, int n4) {
  const int idx = blockIdx.x * 256 + threadIdx.x;
  if (idx >= n4) return;
  const float4 v = ((const float4*)X)[idx];
  u16x4 h, l;
  const float vv[4] = {v.x, v.y, v.z, v.w};
#pragma unroll
  for (int i = 0; i < 4; ++i) {
    h[i] = f32_to_bf16(vv[i]);
    l[i] = f32_to_bf16(vv[i] - bf16_to_f32(h[i]));
  }
  ((u16x4*)hi)[idx] = h;
  ((u16x4*)lo)[idx] = l;
}

// ---------------------------------------------------------------------------
// Row softmax over 4096-wide rows (fp32 in, bf16 out), one block per row.
// ---------------------------------------------------------------------------
__global__ __launch_bounds__(256) void softmax_bf16(const float* __restrict__ Sc,
                                                    u16* __restrict__ P) {
  const long row = blockIdx.x;
  const float* p = Sc + row * 4096L;
  u16* q = P + row * 4096L;
  const int tid = threadIdx.x;

  float r[16];
#pragma unroll
  for (int i = 0; i < 16; ++i) r[i] = p[tid + (i << 8)];

  float m = r[0];
#pragma unroll
  for (int i = 1; i < 16; ++i) m = fmaxf(m, r[i]);
#pragma unroll
  for (int off = 32; off > 0; off >>= 1) m = fmaxf(m, __shfl_down(m, off));

  __shared__ float smax[4];
  __shared__ float ssum[4];
  const int lane = tid & 63;
  const int wv = tid >> 6;
  if (lane == 0) smax[wv] = m;
  __syncthreads();
  m = fmaxf(fmaxf(smax[0], smax[1]), fmaxf(smax[2], smax[3]));

  float s = 0.f;
#pragma unroll
  for (int i = 0; i < 16; ++i) {
    r[i] = __expf(r[i] - m);
    s += r[i];
  }
#pragma unroll
  for (int off = 32; off > 0; off >>= 1) s += __shfl_down(s, off);
  if (lane == 0) ssum[wv] = s;
  __syncthreads();
  s = (ssum[0] + ssum[1]) + (ssum[2] + ssum[3]);

  const float inv = 1.0f / s;
#pragma unroll
  for (int i = 0; i < 16; ++i) q[tid + (i << 8)] = f32_to_bf16(r[i] * inv);
}

// ---------------------------------------------------------------------------
// Workspace layout (byte offsets), 98 MB floor (R2 timing proves ws>=112 MB):
//  0: Wqt_hi/lo, Wkt_hi/lo, Wvt_hi (5 x 2 MB)      [resident]
// 10: Qhi(8) Qlo(8) Khi(8) Klo(8) Vt(8) P(32)      [per batch]
// 82: X region (Xhi 8 + Xlo 8) ALIASED with Sc slab (phase-disjoint)
// ---------------------------------------------------------------------------
extern "C" void kernel_launch(void* const* d_in, const int* in_sizes, int n_in,
                              void* d_out, int out_size, void* d_ws,
                              size_t ws_size, hipStream_t stream) {
  const float* X = (const float*)d_in[0];
  const float* Wq = (const float*)d_in[1];
  const float* Wk = (const float*)d_in[2];
  const float* Wv = (const float*)d_in[3];
  float* out = (float*)d_out;

  const size_t MB = 1 << 20;
  char* w = (char*)d_ws;
  u16* Wqt_hi = (u16*)(w + 0 * MB);
  u16* Wqt_lo = (u16*)(w + 2 * MB);
  u16* Wkt_hi = (u16*)(w + 4 * MB);
  u16* Wkt_lo = (u16*)(w + 6 * MB);
  u16* Wvt_hi = (u16*)(w + 8 * MB);
  u16* Qhi = (u16*)(w + 10 * MB);
  u16* Qlo = (u16*)(w + 18 * MB);
  u16* Khi = (u16*)(w + 26 * MB);
  u16* Klo = (u16*)(w + 34 * MB);
  u16* Vt = (u16*)(w + 42 * MB);   // [CA rows, CS cols] bf16
  u16* P = (u16*)(w + 50 * MB);    // [CS, CS] bf16
  u16* Xhi = (u16*)(w + 82 * MB);
  u16* Xlo = (u16*)(w + 90 * MB);
  float* Sc = (float*)(w + 82 * MB);  // aliases X region (phase-disjoint)

  // pick largest score slab that fits
  long slabQ = 512;
  for (long s = 4096; s >= 512; s >>= 1) {
    size_t region = (size_t)s * CS * 4;
    if (region < 16 * MB) region = 16 * MB;
    if (82 * MB + region <= ws_size) {
      slabQ = s;
      break;
    }
  }

  const dim3 blk(256);

  // weight prep (once per call)
  wtrans_split<<<dim3(32, 32), blk, 0, stream>>>(Wq, Wqt_hi, Wqt_lo);
  wtrans_split<<<dim3(32, 32), blk, 0, stream>>>(Wk, Wkt_hi, Wkt_lo);
  wtrans_split<<<dim3(32, 32), blk, 0, stream>>>(Wv, Wvt_hi, nullptr);

  for (int b = 0; b < CB_; ++b) {
    const float* Xb = X + (long)b * CS * CD;
    float* outb = out + (long)b * CS * CA;

    split_f32<<<dim3(CS * CD / 4 / 256), blk, 0, stream>>>(Xb, Xhi, Xlo,
                                                           CS * CD / 4);

    // projections: [S,D] @ Wt[A,D]^T  (NT), split for Q/K, plain for V
    const dim3 gp(CA / 128, CS / 128);
    gemm_nt<3, 1><<<gp, blk, 0, stream>>>(Xhi, Xlo, Xhi, Wqt_hi, Wqt_hi,
                                          Wqt_lo, Qhi, Qlo, CD, CD, CD, CA);
    gemm_nt<3, 1><<<gp, blk, 0, stream>>>(Xhi, Xlo, Xhi, Wkt_hi, Wkt_hi,
                                          Wkt_lo, Khi, Klo, CD, CD, CD, CA);
    gemm_nt<1, 2><<<gp, blk, 0, stream>>>(Xhi, nullptr, nullptr, Wvt_hi,
                                          nullptr, nullptr, Vt, nullptr, CD,
                                          CD, CD, CS);  // ldc = CS (Vt rows)

    // scores + softmax, slabbed over q
    for (long q0 = 0; q0 < CS; q0 += slabQ) {
      const dim3 gs(CS / 128, slabQ / 128);
      gemm_nt<3, 0><<<gs, blk, 0, stream>>>(
          Qhi + q0 * CA, Qlo + q0 * CA, Qhi + q0 * CA, Khi, Khi, Klo, Sc,
          nullptr, CA, CA, CA, CS);
      softmax_bf16<<<dim3((unsigned)slabQ), blk, 0, stream>>>(Sc,
                                                              P + q0 * CS);
    }

    // out = P @ V  ==  NT(A=P [S,S_k], B=Vt [A,S_k]) -> C[q,a] fp32
    const dim3 gv(CA / 128, CS / 128);
    gemm_nt<1, 0><<<gv, blk, 0, stream>>>(P, nullptr, nullptr, Vt, nullptr,
                                          nullptr, outb, nullptr, CS, CS, CS,
                                          CA);
  }
}